// Round 7
// baseline (232.629 us; speedup 1.0000x reference)
//
#include <hip/hip_runtime.h>
#include <hip/hip_bf16.h>

#define NN 2048
#define FF 64
#define NH 8
#define BDIM 4
#define BH 32        // BDIM*NH

typedef __attribute__((ext_vector_type(8))) short short8;
typedef __attribute__((ext_vector_type(4))) float floatx4;
typedef __attribute__((ext_vector_type(4))) unsigned uint4v;
typedef __attribute__((ext_vector_type(2))) unsigned long long u64x2;

__device__ __forceinline__ float LDIN(const void* p, size_t i, int b16) {
    return b16 ? __bfloat162float(((const __hip_bfloat16*)p)[i]) : ((const float*)p)[i];
}
__device__ __forceinline__ unsigned packhi(float f0, float f1) {
    return __builtin_amdgcn_perm(__float_as_uint(f1), __float_as_uint(f0), 0x07060302);
}
__device__ __forceinline__ float hitrunc(float x) {
    return __uint_as_float(__float_as_uint(x) & 0xFFFF0000u);
}
// XOR-swizzled LDS index (stride 64 shorts, 8-short groups). col must be 4-aligned.
__device__ __forceinline__ int SWZ(int row, int col) {
    return row * 64 + ((((col >> 3) ^ (row & 7)) << 3) | (col & 7));
}
__device__ __forceinline__ float fast_tanh(float v) {
    float ex = __expf(2.0f * v);
    return 1.0f - 2.0f * __builtin_amdgcn_rcpf(ex + 1.0f);
}
__device__ __forceinline__ int sniff_b16(const void* h) {
    unsigned word = ((const unsigned*)h)[threadIdx.x & 63];
    unsigned lowexp = (word >> 7) & 0xFFu;
    bool plaus = (lowexp >= 96u && lowexp <= 159u);
    unsigned long long m = __ballot(plaus);
    return (__popcll(m) >= 48) ? 1 : 0;
}
// monotone float->unsigned map: f0 < f1  <=>  mkey(f0) < mkey(f1)
__device__ __forceinline__ unsigned mkey(float f) {
    unsigned u = __float_as_uint(f);
    return (u & 0x80000000u) ? ~u : (u | 0x80000000u);
}
__device__ __forceinline__ float unmkey(unsigned m) {
    unsigned u = (m & 0x80000000u) ? (m - 0x80000000u) : ~m;
    return __uint_as_float(u);
}

// ---- Kernel 1: MFMA GEMM hp=h@w; fp32 hp rows + s/d/r per row (unchanged) ---
// grid 512 = 32 bh x 16 kb (two 64-row tiles each). 256 thr = 4 waves.
__global__ __launch_bounds__(256) void k_proj(
    const void* __restrict__ h, const void* __restrict__ w,
    const void* __restrict__ asrc, const void* __restrict__ adst,
    float* __restrict__ hpF, float* __restrict__ sArr, float* __restrict__ dArr,
    float* __restrict__ rArr)
{
    const int t = threadIdx.x;
    const int bh = blockIdx.x >> 4, kb = blockIdx.x & 15;
    const int b = bh >> 3, hd = bh & 7;
    const int lane = t & 63, wv = t >> 6;
    const int ml = lane & 15, q = lane >> 4;

    __shared__ ushort aHi[4096];
    __shared__ ushort aLo[4096];
    __shared__ float  sF[64 * 68];
    __shared__ int sb16;
    if (t < 64) { int f = sniff_b16(h); if (t == 0) sb16 = f; }
    __syncthreads();
    const int b16 = sb16;

    short8 bhf[4][2], blf[4][2];
    if (b16) {
        const ushort* wp = (const ushort*)w + (size_t)hd * FF * FF;
#pragma unroll
        for (int nt = 0; nt < 4; ++nt)
#pragma unroll
            for (int kc = 0; kc < 2; ++kc) {
                ushort v[8];
#pragma unroll
                for (int j = 0; j < 8; ++j)
                    v[j] = wp[(kc * 32 + q * 8 + j) * FF + nt * 16 + ml];
                bhf[nt][kc] = *(short8*)v;
            }
    } else {
        const float* wp = (const float*)w + (size_t)hd * FF * FF;
#pragma unroll
        for (int nt = 0; nt < 4; ++nt)
#pragma unroll
            for (int kc = 0; kc < 2; ++kc) {
                float x[8];
#pragma unroll
                for (int j = 0; j < 8; ++j)
                    x[j] = wp[(kc * 32 + q * 8 + j) * FF + nt * 16 + ml];
                uint4v hv = { packhi(x[0], x[1]), packhi(x[2], x[3]),
                              packhi(x[4], x[5]), packhi(x[6], x[7]) };
                uint4v lv = { packhi(x[0] - hitrunc(x[0]), x[1] - hitrunc(x[1])),
                              packhi(x[2] - hitrunc(x[2]), x[3] - hitrunc(x[3])),
                              packhi(x[4] - hitrunc(x[4]), x[5] - hitrunc(x[5])),
                              packhi(x[6] - hitrunc(x[6]), x[7] - hitrunc(x[7])) };
                bhf[nt][kc] = __builtin_bit_cast(short8, hv);
                blf[nt][kc] = __builtin_bit_cast(short8, lv);
            }
    }

    float aS[4], aD[4];
#pragma unroll
    for (int nt = 0; nt < 4; ++nt) {
        aS[nt] = LDIN(asrc, hd * FF + nt * 16 + ml, b16);
        aD[nt] = LDIN(adst, hd * FF + nt * 16 + ml, b16);
    }

#pragma unroll 1
    for (int e = 0; e < 2; ++e) {
        const int r0 = (kb * 2 + e) * 64;
        if (b16) {
            const ushort* hsrc = (const ushort*)h + (size_t)(b * NN + r0) * FF;
#pragma unroll
            for (int g0 = 0; g0 < 2; ++g0) {
                int g = t + g0 * 256;
                int row = g >> 3, c8 = (g & 7) * 8;
                uint4v u = *(const uint4v*)(hsrc + row * FF + c8);
                *(uint4v*)&aHi[SWZ(row, c8)] = u;
            }
        } else {
            const float* hsrc = (const float*)h + (size_t)(b * NN + r0) * FF;
#pragma unroll
            for (int g0 = 0; g0 < 4; ++g0) {
                int g = t + g0 * 256;
                int row = g >> 4, c4 = (g & 15) * 4;
                floatx4 x = *(const floatx4*)(hsrc + row * FF + c4);
                uint2 hi2 = { packhi(x[0], x[1]), packhi(x[2], x[3]) };
                uint2 lo2 = { packhi(x[0] - hitrunc(x[0]), x[1] - hitrunc(x[1])),
                              packhi(x[2] - hitrunc(x[2]), x[3] - hitrunc(x[3])) };
                *(uint2*)&aHi[SWZ(row, c4)] = hi2;
                *(uint2*)&aLo[SWZ(row, c4)] = lo2;
            }
        }
        __syncthreads();

        short8 ah[2], al[2];
#pragma unroll
        for (int kc = 0; kc < 2; ++kc) {
            ah[kc] = *(const short8*)&aHi[SWZ(wv * 16 + ml, kc * 32 + q * 8)];
            if (!b16) al[kc] = *(const short8*)&aLo[SWZ(wv * 16 + ml, kc * 32 + q * 8)];
        }

        floatx4 acc[4];
#pragma unroll
        for (int nt = 0; nt < 4; ++nt) {
            floatx4 a = {0.f, 0.f, 0.f, 0.f};
            if (b16) {
#pragma unroll
                for (int kc = 0; kc < 2; ++kc)
                    a = __builtin_amdgcn_mfma_f32_16x16x32_bf16(ah[kc], bhf[nt][kc], a, 0, 0, 0);
            } else {
#pragma unroll
                for (int kc = 0; kc < 2; ++kc) {
                    a = __builtin_amdgcn_mfma_f32_16x16x32_bf16(ah[kc], bhf[nt][kc], a, 0, 0, 0);
                    a = __builtin_amdgcn_mfma_f32_16x16x32_bf16(ah[kc], blf[nt][kc], a, 0, 0, 0);
                    a = __builtin_amdgcn_mfma_f32_16x16x32_bf16(al[kc], bhf[nt][kc], a, 0, 0, 0);
                }
            }
            acc[nt] = a;
        }

#pragma unroll
        for (int nt = 0; nt < 4; ++nt)
#pragma unroll
            for (int reg = 0; reg < 4; ++reg)
                sF[(wv * 16 + q * 4 + reg) * 68 + nt * 16 + ml] = acc[nt][reg];

        float ps[4] = {0.f, 0.f, 0.f, 0.f}, pd[4] = {0.f, 0.f, 0.f, 0.f};
#pragma unroll
        for (int nt = 0; nt < 4; ++nt)
#pragma unroll
            for (int reg = 0; reg < 4; ++reg) {
                float tv = fast_tanh(acc[nt][reg]);
                ps[reg] += tv * aS[nt];
                pd[reg] += tv * aD[nt];
            }
#pragma unroll
        for (int msk = 1; msk < 16; msk <<= 1)
#pragma unroll
            for (int reg = 0; reg < 4; ++reg) {
                ps[reg] += __shfl_xor(ps[reg], msk, 64);
                pd[reg] += __shfl_xor(pd[reg], msk, 64);
            }
        if (ml == 0) {
#pragma unroll
            for (int reg = 0; reg < 4; ++reg) {
                int i = bh * NN + r0 + wv * 16 + q * 4 + reg;
                float sv = ps[reg], dv = pd[reg];
                sArr[i] = sv;
                dArr[i] = dv;
                rArr[i] = __expf(-0.8f * sv);
            }
        }
        __syncthreads();
        {   // coalesced fp32 row write: each thread stores 16 floats of one row
            const int row = t >> 2, cs = (t & 3) * 16;
            const float* sp = &sF[row * 68 + cs];
            float* dst = hpF + ((size_t)bh * NN + r0 + row) * 64 + cs;
            *(floatx4*)(dst)      = *(const floatx4*)(sp);
            *(floatx4*)(dst + 4)  = *(const floatx4*)(sp + 4);
            *(floatx4*)(dst + 8)  = *(const floatx4*)(sp + 8);
            *(floatx4*)(dst + 12) = *(const floatx4*)(sp + 12);
        }
        __syncthreads();
    }
}

// ---- Kernel 2: rank-by-count (unchanged, proven) ----------------------------
// grid 256 = 32 bh x 8 slabs; 256 thr. rank_j = #{K' > K_j} over packed keys
// (descending d, index tie-break). Scatters SDJ[rank] = (mkey(d)<<32)|j.
__global__ __launch_bounds__(256) void k_rank(
    const float* __restrict__ dArr, unsigned long long* __restrict__ SDJ)
{
    const int bh = blockIdx.x >> 3, slab = blockIdx.x & 7, t = threadIdx.x;
    __shared__ __align__(16) unsigned long long kp[2048];
#pragma unroll
    for (int g = 0; g < 8; ++g) {
        int j = t + g * 256;
        unsigned m = mkey(dArr[bh * NN + j]);
        kp[j] = ((unsigned long long)m << 32) | (unsigned)(2047 - j);
    }
    __syncthreads();
    const int j = slab * 256 + t;
    const unsigned long long K = kp[j];
    int cnt = 0;
#pragma unroll 8
    for (int c = 0; c < 2048; c += 4) {
        u64x2 a = *(const u64x2*)&kp[c];
        u64x2 b = *(const u64x2*)&kp[c + 2];
        cnt += (a.x > K) + (a.y > K) + (b.x > K) + (b.y > K);
    }
    unsigned m = (unsigned)(K >> 32);
    SDJ[bh * NN + cnt] = ((unsigned long long)m << 32) | (unsigned)j;
}

// ---- Kernel 3: fused totals + rowCnt + forward sweep + emit -----------------
// grid 512 = 32 bh x 16 kb; 256 thr = 4 waves; wave wv owns chunk c = kb*4+wv.
// Block redundantly computes ALL 64 chunk totals into LDS (coalesced L2-hot
// gathers, throughput-bound) so the per-wave prefix/suffix is an LDS loop.
// Forward-only walk: Suf(x) = (Tel[c..63] total) - el-prefix  (no history).
__global__ __launch_bounds__(256, 2) void k_sweep(
    const void* __restrict__ h,
    const unsigned long long* __restrict__ SDJ, const float* __restrict__ hpF,
    const float* __restrict__ sArr, const float* __restrict__ rArr,
    const void* __restrict__ bias, void* __restrict__ out)
{
    const int bh = blockIdx.x >> 4, kb = blockIdx.x & 15;
    const int t = threadIdx.x, lane = t & 63, wv = t >> 6;

    __shared__ unsigned long long sdjL[2048];   // 16 KB sorted (m|j)
    __shared__ ushort cntL[2048];               // 4 KB  per-row cnt
    __shared__ float TehL[64][64];              // 16 KB chunk totals eh*hp
    __shared__ float TelL[64][64];              // 16 KB chunk totals el*hp
    __shared__ float TehSs[64], TelSs[64];      // scalar totals
    __shared__ unsigned listW[4][512];          // 8 KB  per-wave (cnt,i) lists
    __shared__ int sb16;
    if (t < 64) { int f = sniff_b16(h); if (t == 0) sb16 = f; }

#pragma unroll
    for (int g = 0; g < 8; ++g)
        sdjL[t + g * 256] = SDJ[bh * NN + t + g * 256];
    __syncthreads();
    const int b16 = sb16;

    // rowCnt: binary search over descending hi-words of sdjL (11 LDS steps)
#pragma unroll
    for (int g = 0; g < 8; ++g) {
        int i = t + g * 256;
        unsigned mthr = mkey(-sArr[bh * NN + i]);
        int lo = 0, hi = 2048;
        while (lo < hi) {
            int m = (lo + hi) >> 1;
            if ((unsigned)(sdjL[m] >> 32) >= mthr) lo = m + 1; else hi = m;
        }
        cntL[i] = (ushort)lo;
    }

    // all-64 chunk totals: wave wv computes chunks [wv*16, wv*16+16)
#pragma unroll 1
    for (int cc = 0; cc < 16; ++cc) {
        const int c = wv * 16 + cc;
        float teh = 0.f, tel = 0.f, tehs = 0.f, tels = 0.f;
#pragma unroll 4
        for (int u = 0; u < 32; ++u) {
            unsigned long long K = sdjL[c * 32 + u];
            int jj = (int)(K & 0xFFFFFFFFu);
            float d = unmkey((unsigned)(K >> 32));
            float eh = __expf(d), el = __expf(0.2f * d);
            float hv = hpF[((size_t)bh * NN + jj) * 64 + lane];
            teh += eh * hv; tel += el * hv; tehs += eh; tels += el;
        }
        TehL[c][lane] = teh; TelL[c][lane] = tel;
        if (lane == 0) { TehSs[c] = tehs; TelSs[c] = tels; }
    }
    __syncthreads();

    // ---- per-wave: own chunk c ----
    const int c = kb * 4 + wv;
    float preV = 0.f, preS = 0.f;
    for (int cp = 0; cp < c; ++cp) { preV += TehL[cp][lane]; preS += TehSs[cp]; }
    float sufAll = 0.f, sufAllS = 0.f;
    for (int cp = 63; cp >= c; --cp) { sufAll += TelL[cp][lane]; sufAllS += TelSs[cp]; }

    // preload own chunk: d + hv rows (independent loads, fully unrolled)
    float dv[32], hvv[32];
#pragma unroll
    for (int u = 0; u < 32; ++u) {
        unsigned long long K = sdjL[c * 32 + u];
        dv[u] = unmkey((unsigned)(K >> 32));
        hvv[u] = hpF[((size_t)bh * NN + (int)(K & 0xFFFFFFFFu)) * 64 + lane];
    }

    // list build: ballot + popcount compaction (no atomics)
    const int xlo = c * 32, xhi = (c == 63) ? 2049 : (c * 32 + 32);
    int base = 0;
#pragma unroll 1
    for (int g = 0; g < 32; ++g) {
        int i = g * 64 + lane;
        int cn = cntL[i];
        bool m0 = (cn >= xlo && cn < xhi);
        unsigned long long mask = __ballot(m0);
        if (m0) {
            int off = __popcll(mask & ((1ULL << lane) - 1ULL));
            if (base + off < 512)
                listW[wv][base + off] = ((unsigned)cn << 11) | (unsigned)i;
        }
        base += (int)__popcll(mask);
    }
    const int len = base < 512 ? base : 512;
    const bool slow = (base > 512);     // ~impossible; correctness fallback

    const size_t obase = (size_t)bh * NN;
    const float biasv = LDIN(bias, lane, b16);

    float ehRun = 0.f, ehRunS = 0.f, elRun = 0.f, elRunS = 0.f;
    const int uMax = (c == 63) ? 33 : 32;
#pragma unroll 1
    for (int u = 0; u < uMax; ++u) {
        const int x = c * 32 + u;
        // emit rows with cnt == x (Pre excludes rank x; Suf includes it)
        if (!slow) {
            for (int s0 = 0; s0 < len; s0 += 64) {
                int sl = s0 + lane;
                unsigned e = (sl < len) ? listW[wv][sl] : 0xFFFFFFFFu;
                unsigned long long mask = __ballot(sl < len && (int)(e >> 11) == x);
                while (mask) {
                    int l = __ffsll((long long)mask) - 1; mask &= mask - 1;
                    unsigned ee = listW[wv][s0 + l];       // broadcast LDS read
                    int i = (int)(ee & 2047u);
                    float rr = rArr[obase + i];
                    float val = ((preV + ehRun) + rr * (sufAll - elRun))
                              / ((preS + ehRunS) + rr * (sufAllS - elRunS)) + biasv;
                    size_t oi = (obase + i) * 64 + lane;
                    if (b16) ((__hip_bfloat16*)out)[oi] = __float2bfloat16(val);
                    else     ((float*)out)[oi] = val;
                }
            }
        } else {
            for (int g = 0; g < 32; ++g) {
                int i0 = g * 64 + lane;
                int cn = cntL[i0];
                unsigned long long mask = __ballot(cn == x);
                while (mask) {
                    int l = __ffsll((long long)mask) - 1; mask &= mask - 1;
                    int i = g * 64 + l;
                    float rr = rArr[obase + i];
                    float val = ((preV + ehRun) + rr * (sufAll - elRun))
                              / ((preS + ehRunS) + rr * (sufAllS - elRunS)) + biasv;
                    size_t oi = (obase + i) * 64 + lane;
                    if (b16) ((__hip_bfloat16*)out)[oi] = __float2bfloat16(val);
                    else     ((float*)out)[oi] = val;
                }
            }
        }
        if (u < 32) {
            float eh = __expf(dv[u]), el = __expf(0.2f * dv[u]);
            ehRun += eh * hvv[u]; ehRunS += eh;
            elRun += el * hvv[u]; elRunS += el;
        }
    }
}

extern "C" void kernel_launch(void* const* d_in, const int* in_sizes, int n_in,
                              void* d_out, int out_size, void* d_ws, size_t ws_size,
                              hipStream_t stream) {
    const void* h    = d_in[0];
    // d_in[1] = adj (bool) — unused by reference
    const void* w    = d_in[2];
    const void* asrc = d_in[3];
    const void* adst = d_in[4];
    const void* bias = d_in[5];

    float* ws = (float*)d_ws;
    float*  hpF  = ws;                                    // 32*2048*64 fp32 (16 MB)
    float*  sArr = hpF + (size_t)BH * NN * FF;            // 65536
    float*  dArr = sArr + BH * NN;
    float*  rArr = dArr + BH * NN;
    unsigned long long* SDJ = (unsigned long long*)(rArr + BH * NN); // 65536 u64

    k_proj<<<BH * 16, 256, 0, stream>>>(h, w, asrc, adst, hpF, sArr, dArr, rArr);
    k_rank<<<BH * 8, 256, 0, stream>>>(dArr, SDJ);
    k_sweep<<<BH * 16, 256, 0, stream>>>(h, SDJ, hpF, sArr, rArr, bias, d_out);
}